// Round 1
// baseline (2158.400 us; speedup 1.0000x reference)
//
#include <hip/hip_runtime.h>
#include <math.h>

#define HD   32      // hidden size H
#define NG   128     // 4*H gates
#define TT   512     // sequence length
#define DD   6       // input feature dim
#define EPSL 1e-5f

// sigmoid(x) = 1/(1+exp(-x)); tanh(x) = 2*sigmoid(2x)-1  (one v_exp + one rcp each)
__device__ __forceinline__ float act_gate(float x, bool is_tanh) {
    float xx = is_tanh ? 2.0f * x : x;
    float s  = 1.0f / (1.0f + __expf(-xx));
    return is_tanh ? 2.0f * s - 1.0f : s;
}

__device__ __forceinline__ float tanh_fast(float x) {
    // 1 - 2/(exp(2x)+1); correct saturation at +/-inf
    return 1.0f - 2.0f / (__expf(2.0f * x) + 1.0f);
}

__global__ __launch_bounds__(128, 3) void lstm2_ln_fused(
    const float* __restrict__ x,      // (B,T,D)
    const float* __restrict__ W_ih0,  // (128,6)
    const float* __restrict__ W_hh0,  // (128,32)
    const float* __restrict__ b_ih0,  // (128)
    const float* __restrict__ b_hh0,  // (128)
    const float* __restrict__ W_ih1,  // (128,32)
    const float* __restrict__ W_hh1,  // (128,32)
    const float* __restrict__ b_ih1,  // (128)
    const float* __restrict__ b_hh1,  // (128)
    const float* __restrict__ gamma,  // (32)
    const float* __restrict__ beta,   // (32)
    float* __restrict__ out)          // (B,32)
{
    const int b = blockIdx.x;
    const int g = threadIdx.x;          // 0..127, one gate per thread

    __shared__ float h0_s[HD];
    __shared__ float h1_s[HD];
    __shared__ float gates0_s[NG];
    __shared__ float gates1_s[NG];
    __shared__ float x_s[2][DD];

    // ---- per-thread weights in registers (reused 512x) ----
    float wi0[DD], wh0[HD], wi1[HD], wh1[HD];
    {
        const float* p = W_ih0 + g * DD;
        #pragma unroll
        for (int d = 0; d < DD; ++d) wi0[d] = p[d];
    }
    {
        const float4* p = (const float4*)(W_hh0 + g * HD);
        #pragma unroll
        for (int q = 0; q < HD / 4; ++q) {
            float4 v = p[q];
            wh0[4*q+0] = v.x; wh0[4*q+1] = v.y; wh0[4*q+2] = v.z; wh0[4*q+3] = v.w;
        }
    }
    {
        const float4* p = (const float4*)(W_ih1 + g * HD);
        #pragma unroll
        for (int q = 0; q < HD / 4; ++q) {
            float4 v = p[q];
            wi1[4*q+0] = v.x; wi1[4*q+1] = v.y; wi1[4*q+2] = v.z; wi1[4*q+3] = v.w;
        }
    }
    {
        const float4* p = (const float4*)(W_hh1 + g * HD);
        #pragma unroll
        for (int q = 0; q < HD / 4; ++q) {
            float4 v = p[q];
            wh1[4*q+0] = v.x; wh1[4*q+1] = v.y; wh1[4*q+2] = v.z; wh1[4*q+3] = v.w;
        }
    }
    const float bias0 = b_ih0[g] + b_hh0[g];
    const float bias1 = b_ih1[g] + b_hh1[g];
    const bool  is_tanh_gate = (g >= 2 * HD) && (g < 3 * HD);

    const float* xb = x + (size_t)b * TT * DD;

    // ---- init state ----
    if (g < HD) { h0_s[g] = 0.0f; h1_s[g] = 0.0f; }
    if (g < DD) { x_s[0][g] = xb[g]; }
    float c0 = 0.0f, c1 = 0.0f;   // owned by threads g < 32
    __syncthreads();

    for (int t = 0; t < TT; ++t) {
        // ========== (A) layer-0 gates ==========
        {
            const float* xs = x_s[t & 1];
            float a0 = bias0, a1 = 0.0f, a2 = 0.0f, a3 = 0.0f;
            a0 += wi0[0] * xs[0]; a1 += wi0[1] * xs[1];
            a2 += wi0[2] * xs[2]; a3 += wi0[3] * xs[3];
            a0 += wi0[4] * xs[4]; a1 += wi0[5] * xs[5];
            const float4* hv = (const float4*)h0_s;
            #pragma unroll
            for (int q = 0; q < HD / 4; ++q) {
                float4 h4 = hv[q];
                a0 += wh0[4*q+0] * h4.x;
                a1 += wh0[4*q+1] * h4.y;
                a2 += wh0[4*q+2] * h4.z;
                a3 += wh0[4*q+3] * h4.w;
            }
            gates0_s[g] = act_gate((a0 + a1) + (a2 + a3), is_tanh_gate);
        }
        __syncthreads();

        // ========== (B) layer-0 state update (wave 0) + x prefetch (wave 1) ==========
        if (g < HD) {
            float iv = gates0_s[g];
            float fv = gates0_s[HD + g];
            float gv = gates0_s[2 * HD + g];
            float ov = gates0_s[3 * HD + g];
            c0 = fv * c0 + iv * gv;
            h0_s[g] = ov * tanh_fast(c0);
        } else if (g >= 96 && g < 96 + DD) {
            int t1 = t + 1;
            if (t1 < TT) x_s[t1 & 1][g - 96] = xb[t1 * DD + (g - 96)];
        }
        __syncthreads();

        // ========== (C) layer-1 gates ==========
        {
            float a0 = bias1, a1 = 0.0f, a2 = 0.0f, a3 = 0.0f;
            const float4* h0v = (const float4*)h0_s;
            const float4* h1v = (const float4*)h1_s;
            #pragma unroll
            for (int q = 0; q < HD / 4; ++q) {
                float4 h4 = h0v[q];
                a0 += wi1[4*q+0] * h4.x;
                a1 += wi1[4*q+1] * h4.y;
                a2 += wi1[4*q+2] * h4.z;
                a3 += wi1[4*q+3] * h4.w;
            }
            #pragma unroll
            for (int q = 0; q < HD / 4; ++q) {
                float4 h4 = h1v[q];
                a0 += wh1[4*q+0] * h4.x;
                a1 += wh1[4*q+1] * h4.y;
                a2 += wh1[4*q+2] * h4.z;
                a3 += wh1[4*q+3] * h4.w;
            }
            gates1_s[g] = act_gate((a0 + a1) + (a2 + a3), is_tanh_gate);
        }
        __syncthreads();

        // ========== (D) layer-1 state update ==========
        if (g < HD) {
            float iv = gates1_s[g];
            float fv = gates1_s[HD + g];
            float gv = gates1_s[2 * HD + g];
            float ov = gates1_s[3 * HD + g];
            c1 = fv * c1 + iv * gv;
            h1_s[g] = ov * tanh_fast(c1);
        }
        __syncthreads();
    }

    // ---- LayerNorm over final h1 (threads 0..31) ----
    if (g < HD) {
        float s = 0.0f, s2 = 0.0f;
        #pragma unroll
        for (int k = 0; k < HD; ++k) {
            float v = h1_s[k];
            s += v; s2 += v * v;
        }
        float mu  = s * (1.0f / HD);
        float var = s2 * (1.0f / HD) - mu * mu;
        float r   = rsqrtf(var + EPSL);
        out[(size_t)b * HD + g] = (h1_s[g] - mu) * r * gamma[g] + beta[g];
    }
}

extern "C" void kernel_launch(void* const* d_in, const int* in_sizes, int n_in,
                              void* d_out, int out_size, void* d_ws, size_t ws_size,
                              hipStream_t stream) {
    const float* x     = (const float*)d_in[0];
    const float* W_ih0 = (const float*)d_in[1];
    const float* W_hh0 = (const float*)d_in[2];
    const float* b_ih0 = (const float*)d_in[3];
    const float* b_hh0 = (const float*)d_in[4];
    const float* W_ih1 = (const float*)d_in[5];
    const float* W_hh1 = (const float*)d_in[6];
    const float* b_ih1 = (const float*)d_in[7];
    const float* b_hh1 = (const float*)d_in[8];
    const float* gamma = (const float*)d_in[9];
    const float* beta  = (const float*)d_in[10];
    float* out = (float*)d_out;

    const int B = in_sizes[0] / (TT * DD);   // 4096

    lstm2_ln_fused<<<B, NG, 0, stream>>>(x, W_ih0, W_hh0, b_ih0, b_hh0,
                                         W_ih1, W_hh1, b_ih1, b_hh1,
                                         gamma, beta, out);
}

// Round 2
// 695.661 us; speedup vs baseline: 3.1027x; 3.1027x over previous
//
#include <hip/hip_runtime.h>

// ---------------- problem constants ----------------
#define TT   512
#define DD   6
#define HD   32
#define EPSL 1e-5f

typedef __attribute__((ext_vector_type(8))) short  short8;   // 8 bf16 (4 VGPR) MFMA A/B frag
typedef __attribute__((ext_vector_type(4))) float  f32x4;    // MFMA C/D frag

#define MFMA(a, b, c) __builtin_amdgcn_mfma_f32_16x16x32_bf16((a), (b), (c), 0, 0, 0)

// fp32 -> bf16 round-to-nearest-even (manual, branchless)
__device__ __forceinline__ unsigned short bf_rne(float x) {
    unsigned u = __float_as_uint(x);
    unsigned r = u + 0x7fffu + ((u >> 16) & 1u);
    return (unsigned short)(r >> 16);
}
__device__ __forceinline__ float bf_tof(unsigned short h) {
    return __uint_as_float(((unsigned)h) << 16);
}
__device__ __forceinline__ float sigm(float v) {
    float e = __builtin_amdgcn_exp2f(-1.44269504f * v);
    return __builtin_amdgcn_rcpf(1.0f + e);
}
__device__ __forceinline__ float tanh_f(float v) {
    float e = __builtin_amdgcn_exp2f(-2.88539008f * v);
    return fmaf(2.0f, __builtin_amdgcn_rcpf(1.0f + e), -1.0f);
}

// pack 8 fp32 (two float4) into hi/lo bf16 frags (3-term split source)
#define PK(j, val) { unsigned short t_ = bf_rne(val); hi[j] = (short)t_; \
                     lo[j] = (short)bf_rne((val) - bf_tof(t_)); }
__device__ __forceinline__ void pack8(float4 a, float4 b, short8& hi, short8& lo) {
    PK(0, a.x) PK(1, a.y) PK(2, a.z) PK(3, a.w)
    PK(4, b.x) PK(5, b.y) PK(6, b.z) PK(7, b.w)
}

// ====================================================================
// One block = 16 batch rows (one MFMA M-tile). 2 waves:
//   wave uh owns N-tiles {2p+uh : p=0..3} = gates {i,f,g,o} of units 16uh..16uh+15.
// Verified gfx950 16x16x32 layouts (learn_hip m89/m120):
//   A[m][k]:  m = lane&15,        k = (lane>>4)*8 + j   (j=0..7 in frag)
//   B[k][n]:  n = lane&15,        k = (lane>>4)*8 + j
//   D[m][n]:  n = lane&15,        m = (lane>>4)*4 + reg
// => lane (q,n) of wave uh holds, for reg r: gate value of
//    (batch m = 4q+r, unit u = 16uh + n) for each gate type p. Cell update is
//    lane-local; only h crosses waves via LDS planes.
// ====================================================================
__global__ __launch_bounds__(128, 1) void lstm2_mfma(
    const float* __restrict__ x,      // (B,512,6)
    const float* __restrict__ W_ih0,  // (128,6)
    const float* __restrict__ W_hh0,  // (128,32)
    const float* __restrict__ b_ih0,
    const float* __restrict__ b_hh0,
    const float* __restrict__ W_ih1,  // (128,32)
    const float* __restrict__ W_hh1,  // (128,32)
    const float* __restrict__ b_ih1,
    const float* __restrict__ b_hh1,
    const float* __restrict__ gamma,
    const float* __restrict__ beta,
    float* __restrict__ out)          // (B,32)
{
    const int tid = threadIdx.x;
    const int uh  = tid >> 6;      // wave id = unit half
    const int ln  = tid & 63;
    const int q   = ln >> 4;       // quad
    const int n   = ln & 15;       // tile col (unit) / batch row for A-frags
    const int u   = 16 * uh + n;   // global unit index for this lane's D cols
    const int b0  = blockIdx.x << 4;

    // h planes: [layer][buf][hi|lo][m=16][k=unit, padded to 40 shorts (80B, 16B-aligned rows)]
    __shared__ __align__(16) unsigned short hbuf[2][2][2][16][40];
    __shared__ float ln_s[16][33];

    { // zero h planes (t=0 state: h=0)
        unsigned* p = (unsigned*)&hbuf[0][0][0][0][0];
        for (int i = tid; i < (int)(sizeof(hbuf) / 4); i += 128) p[i] = 0u;
    }

    // ---------------- prologue: pack weight B-frags into registers ----------------
    // B-frag element j of lane (q,n): B[k=8q+j][n] = W[gate g][k]  (B = W^T)
#define SETUP_P(p) \
    short8 B0hh##p, B0hl##p, B1ah##p, B1al##p, B1bh##p, B1bl##p; \
    short8 Bx##p = {0,0,0,0,0,0,0,0}; \
    float bias0_##p, bias1_##p; \
    { \
        const int g = 32 * (p) + u; \
        const float4* r4; \
        r4 = (const float4*)(W_hh0 + g * 32 + 8 * q); pack8(r4[0], r4[1], B0hh##p, B0hl##p); \
        r4 = (const float4*)(W_ih1 + g * 32 + 8 * q); pack8(r4[0], r4[1], B1ah##p, B1al##p); \
        r4 = (const float4*)(W_hh1 + g * 32 + 8 * q); pack8(r4[0], r4[1], B1bh##p, B1bl##p); \
        if (q == 0) { /* x-chunk: rows k=0..5 are the D=6 input dims (1-term) */ \
            Bx##p[0] = (short)bf_rne(W_ih0[g * 6 + 0]); \
            Bx##p[1] = (short)bf_rne(W_ih0[g * 6 + 1]); \
            Bx##p[2] = (short)bf_rne(W_ih0[g * 6 + 2]); \
            Bx##p[3] = (short)bf_rne(W_ih0[g * 6 + 3]); \
            Bx##p[4] = (short)bf_rne(W_ih0[g * 6 + 4]); \
            Bx##p[5] = (short)bf_rne(W_ih0[g * 6 + 5]); \
        } \
        bias0_##p = b_ih0[g] + b_hh0[g]; \
        bias1_##p = b_ih1[g] + b_hh1[g]; \
    }
    SETUP_P(0) SETUP_P(1) SETUP_P(2) SETUP_P(3)

    // per-lane x stream (A-frag m = n => lanes of quad 0 carry batch n's x)
    const float* xp = x + (size_t)(b0 + n) * (TT * DD);
    float2 xa = {0,0}, xb = {0,0}, xc = {0,0};
    if (q == 0) { // t = 0 prefetch (24B row, 8B-aligned float2 loads)
        const float2* p2 = (const float2*)xp;
        xa = p2[0]; xb = p2[1]; xc = p2[2];
    }

    // cell state: c for (m = 4q+r, u); lane-local fp32
    float c00 = 0.f, c01 = 0.f, c02 = 0.f, c03 = 0.f;
    float c10 = 0.f, c11 = 0.f, c12 = 0.f, c13 = 0.f;
    float hL0 = 0.f, hL1 = 0.f, hL2 = 0.f, hL3 = 0.f;  // last fp32 h1 (for LN)

    __syncthreads();

    #pragma unroll 1
    for (int t = 0; t < TT; ++t) {
        const int rb = t & 1;       // read buffer (h at t-1)
        const int wb = rb ^ 1;      // write buffer (h at t)

        // ---- build x A-frag from prefetched regs, then prefetch t+1 ----
        short8 Ax = {0,0,0,0,0,0,0,0};
        if (q == 0) {
            Ax[0] = (short)bf_rne(xa.x); Ax[1] = (short)bf_rne(xa.y);
            Ax[2] = (short)bf_rne(xb.x); Ax[3] = (short)bf_rne(xb.y);
            Ax[4] = (short)bf_rne(xc.x); Ax[5] = (short)bf_rne(xc.y);
            const int tn = (t < TT - 1) ? t + 1 : t;
            const float2* p2 = (const float2*)(xp + (size_t)tn * DD);
            xa = p2[0]; xb = p2[1]; xc = p2[2];
        }

        // ---- G0: gates0 = [h0_{t-1} | x_t] . B0  (A-frag: m=n is batch) ----
        short8 A0h = *(const short8*)&hbuf[0][rb][0][n][8 * q];
        short8 A0l = *(const short8*)&hbuf[0][rb][1][n][8 * q];

#define G0_P(p, ACC) \
        f32x4 ACC = {bias0_##p, bias0_##p, bias0_##p, bias0_##p}; \
        ACC = MFMA(A0h, B0hh##p, ACC); \
        ACC = MFMA(A0l, B0hh##p, ACC); \
        ACC = MFMA(A0h, B0hl##p, ACC); \
        ACC = MFMA(Ax,  Bx##p,   ACC);
        G0_P(0, g0i) G0_P(1, g0f) G0_P(2, g0g) G0_P(3, g0o)

        // ---- U0: lane-local cell update; publish h0_t hi/lo to LDS ----
#define U0_R(r) { \
        float iv = sigm(g0i[r]); float fv = sigm(g0f[r]); \
        float gv = tanh_f(g0g[r]); float ov = sigm(g0o[r]); \
        c0##r = fv * c0##r + iv * gv; \
        float h_ = ov * tanh_f(c0##r); \
        unsigned short hh_ = bf_rne(h_); \
        unsigned short hl_ = bf_rne(h_ - bf_tof(hh_)); \
        hbuf[0][wb][0][4 * q + r][u] = hh_; \
        hbuf[0][wb][1][4 * q + r][u] = hl_; }
        U0_R(0) U0_R(1) U0_R(2) U0_R(3)

        __syncthreads();

        // ---- G1: gates1 = [h0_t | h1_{t-1}] . B1 ----
        short8 A0h2 = *(const short8*)&hbuf[0][wb][0][n][8 * q];
        short8 A0l2 = *(const short8*)&hbuf[0][wb][1][n][8 * q];
        short8 A1h  = *(const short8*)&hbuf[1][rb][0][n][8 * q];
        short8 A1l  = *(const short8*)&hbuf[1][rb][1][n][8 * q];

#define G1_P(p, ACC) \
        f32x4 ACC = {bias1_##p, bias1_##p, bias1_##p, bias1_##p}; \
        ACC = MFMA(A0h2, B1ah##p, ACC); \
        ACC = MFMA(A0l2, B1ah##p, ACC); \
        ACC = MFMA(A0h2, B1al##p, ACC); \
        ACC = MFMA(A1h,  B1bh##p, ACC); \
        ACC = MFMA(A1l,  B1bh##p, ACC); \
        ACC = MFMA(A1h,  B1bl##p, ACC);
        G1_P(0, g1i) G1_P(1, g1f) G1_P(2, g1g) G1_P(3, g1o)

        // ---- U1: update c1/h1; publish; keep fp32 h1 for LN ----
#define U1_R(r) { \
        float iv = sigm(g1i[r]); float fv = sigm(g1f[r]); \
        float gv = tanh_f(g1g[r]); float ov = sigm(g1o[r]); \
        c1##r = fv * c1##r + iv * gv; \
        float h_ = ov * tanh_f(c1##r); \
        hL##r = h_; \
        unsigned short hh_ = bf_rne(h_); \
        unsigned short hl_ = bf_rne(h_ - bf_tof(hh_)); \
        hbuf[1][wb][0][4 * q + r][u] = hh_; \
        hbuf[1][wb][1][4 * q + r][u] = hl_; }
        U1_R(0) U1_R(1) U1_R(2) U1_R(3)

        __syncthreads();
    }

    // ---------------- LayerNorm epilogue ----------------
    ln_s[4 * q + 0][u] = hL0;
    ln_s[4 * q + 1][u] = hL1;
    ln_s[4 * q + 2][u] = hL2;
    ln_s[4 * q + 3][u] = hL3;
    __syncthreads();

    if (tid < 16) {
        const int m = tid;
        float s = 0.f, s2 = 0.f;
        #pragma unroll
        for (int k = 0; k < HD; ++k) {
            float v = ln_s[m][k];
            s += v; s2 += v * v;
        }
        float mu  = s * (1.0f / HD);
        float var = s2 * (1.0f / HD) - mu * mu;
        float rr  = rsqrtf(var + EPSL);
        float* op = out + (size_t)(b0 + m) * HD;
        #pragma unroll
        for (int k = 0; k < HD; ++k)
            op[k] = (ln_s[m][k] - mu) * rr * gamma[k] + beta[k];
    }
}

extern "C" void kernel_launch(void* const* d_in, const int* in_sizes, int n_in,
                              void* d_out, int out_size, void* d_ws, size_t ws_size,
                              hipStream_t stream) {
    const float* x     = (const float*)d_in[0];
    const float* W_ih0 = (const float*)d_in[1];
    const float* W_hh0 = (const float*)d_in[2];
    const float* b_ih0 = (const float*)d_in[3];
    const float* b_hh0 = (const float*)d_in[4];
    const float* W_ih1 = (const float*)d_in[5];
    const float* W_hh1 = (const float*)d_in[6];
    const float* b_ih1 = (const float*)d_in[7];
    const float* b_hh1 = (const float*)d_in[8];
    const float* gamma = (const float*)d_in[9];
    const float* beta  = (const float*)d_in[10];
    float* out = (float*)d_out;

    const int B = in_sizes[0] / (TT * DD);   // 4096
    lstm2_mfma<<<B / 16, 128, 0, stream>>>(x, W_ih0, W_hh0, b_ih0, b_hh0,
                                           W_ih1, W_hh1, b_ih1, b_hh1,
                                           gamma, beta, out);
}

// Round 3
// 456.116 us; speedup vs baseline: 4.7321x; 1.5252x over previous
//
#include <hip/hip_runtime.h>

#define TT   512
#define DD   6
#define HD   32
#define EPSL 1e-5f

typedef _Float16 half8 __attribute__((ext_vector_type(8)));
typedef __attribute__((ext_vector_type(4))) float f32x4;

#define MFMA_F16(a, b, c) __builtin_amdgcn_mfma_f32_16x16x32_f16((a), (b), (c), 0, 0, 0)

__device__ __forceinline__ float sigm(float v) {
    float e = __builtin_amdgcn_exp2f(-1.44269504f * v);
    return __builtin_amdgcn_rcpf(1.0f + e);
}
__device__ __forceinline__ float tanh_f(float v) {
    float e = __builtin_amdgcn_exp2f(-2.88539008f * v);
    return fmaf(2.0f, __builtin_amdgcn_rcpf(1.0f + e), -1.0f);
}

// ====================================================================
// Layer-pipelined 2-layer LSTM. One block = one 16-batch M-tile, 4 waves:
//   wave w: L = w>>1 (layer role), uh = w&1 (unit half).
// Iteration s (s = 0..TT, one __syncthreads each):
//   L0 waves process t0 = s     (while s < TT)
//   L1 waves process t1 = s - 1 (while s >= 1)   -- one-step skew
// h0/h1 live in double-buffered fp16 LDS rings. fp16 1-term MFMA
// (2^-11 rel err; tighter than R2's bf16 x-path at 2^-9).
// 16x16x32 layouts (verified learn_hip m89/m120):
//   A[m][k]: m=lane&15, k=(lane>>4)*8+j ;  B[k][n]: n=lane&15, k=(lane>>4)*8+j
//   D[m][n]: n=lane&15, m=(lane>>4)*4+reg  -> cell update is lane-local.
// ====================================================================
__global__ __launch_bounds__(256, 1) void lstm2_pipe(
    const float* __restrict__ x,      // (B,512,6)
    const float* __restrict__ W_ih0,  // (128,6)
    const float* __restrict__ W_hh0,  // (128,32)
    const float* __restrict__ b_ih0,
    const float* __restrict__ b_hh0,
    const float* __restrict__ W_ih1,  // (128,32)
    const float* __restrict__ W_hh1,  // (128,32)
    const float* __restrict__ b_ih1,
    const float* __restrict__ b_hh1,
    const float* __restrict__ gamma,
    const float* __restrict__ beta,
    float* __restrict__ out)          // (B,32)
{
    const int tid = threadIdx.x;
    const int w   = tid >> 6;
    const int L   = w >> 1;        // 0: layer-0 role, 1: layer-1 role
    const int uh  = w & 1;         // unit half
    const int ln  = tid & 63;
    const int q   = ln >> 4;
    const int n   = ln & 15;
    const int u   = 16 * uh + n;
    const int b0  = blockIdx.x << 4;

    // fp16 h rings: [buf][m=16][k=unit padded to 40] (row 80B, 16B-aligned)
    __shared__ __align__(16) _Float16 h0r[2][16][40];
    __shared__ __align__(16) _Float16 h1r[2][16][40];
    __shared__ float ln_s[16][33];

    {   // zero both rings (t<0 state: h = 0)
        unsigned* p0 = (unsigned*)&h0r[0][0][0];
        for (int i = tid; i < (int)(sizeof(h0r) / 4); i += 256) p0[i] = 0u;
        unsigned* p1 = (unsigned*)&h1r[0][0][0];
        for (int i = tid; i < (int)(sizeof(h1r) / 4); i += 256) p1[i] = 0u;
    }

    // ---------------- weight B-frags (fp16, 1-term) ----------------
    // L0: Ba = W_hh0^T frag, Bb = zero-padded W_ih0^T (x-chunk, k=0..5)
    // L1: Ba = W_ih1^T frag, Bb = W_hh1^T frag
    const float* Wa = L ? W_ih1 : W_hh0;
    const float* bi = L ? b_ih1 : b_ih0;
    const float* bh = L ? b_hh1 : b_hh0;

#define SETUP(p) \
    half8 Ba##p, Bb##p; float bias##p; { \
        const int g = 32 * (p) + u; \
        const float4* r4 = (const float4*)(Wa + g * 32 + 8 * q); \
        float4 va = r4[0], vb = r4[1]; \
        Ba##p = half8{(_Float16)va.x, (_Float16)va.y, (_Float16)va.z, (_Float16)va.w, \
                      (_Float16)vb.x, (_Float16)vb.y, (_Float16)vb.z, (_Float16)vb.w}; \
        Bb##p = half8{0, 0, 0, 0, 0, 0, 0, 0}; \
        if (L) { \
            const float4* s4 = (const float4*)(W_hh1 + g * 32 + 8 * q); \
            float4 sa = s4[0], sb = s4[1]; \
            Bb##p = half8{(_Float16)sa.x, (_Float16)sa.y, (_Float16)sa.z, (_Float16)sa.w, \
                          (_Float16)sb.x, (_Float16)sb.y, (_Float16)sb.z, (_Float16)sb.w}; \
        } else if (q == 0) { \
            const float* xw = W_ih0 + g * 6; \
            Bb##p[0] = (_Float16)xw[0]; Bb##p[1] = (_Float16)xw[1]; \
            Bb##p[2] = (_Float16)xw[2]; Bb##p[3] = (_Float16)xw[3]; \
            Bb##p[4] = (_Float16)xw[4]; Bb##p[5] = (_Float16)xw[5]; \
        } \
        bias##p = bi[g] + bh[g]; \
    }
    SETUP(0) SETUP(1) SETUP(2) SETUP(3)

    // x stream: A-frag row m = n -> q==0 lanes of L0 waves carry batch (b0+n)'s x
    const float* xp = x + (size_t)(b0 + n) * (TT * DD);
    float2 xa = {0, 0}, xb = {0, 0}, xc = {0, 0};
    if (L == 0 && q == 0) {
        const float2* p2 = (const float2*)xp;   // x(0)
        xa = p2[0]; xb = p2[1]; xc = p2[2];
    }

    float cc0 = 0.f, cc1 = 0.f, cc2 = 0.f, cc3 = 0.f;   // cell state (lane-local)
    float hL0 = 0.f, hL1 = 0.f, hL2 = 0.f, hL3 = 0.f;   // fp32 h1 (LN epilogue)

    __syncthreads();

    #pragma unroll 1
    for (int s = 0; s <= TT; ++s) {
        const int wsl = s & 1;
        const int rsl = wsl ^ 1;
        const bool active = L ? (s >= 1) : (s < TT);
        if (active) {
            // Aa: h0 ring slot rsl. L0: h0(t0-1)=h0(s-1) in slot (s-1)&1=rsl.
            //                       L1: h0(t1) =h0(s-1) same slot.  (unified!)
            half8 Aa = *(const half8*)&h0r[rsl][n][8 * q];
            half8 Ab;
            if (L) {
                // h1(t1-1) = h1(s-2): written at iter s-1 to slot (s-2)&1 = wsl
                Ab = *(const half8*)&h1r[wsl][n][8 * q];
            } else {
                Ab = half8{0, 0, 0, 0, 0, 0, 0, 0};
                if (q == 0) {
                    Ab[0] = (_Float16)xa.x; Ab[1] = (_Float16)xa.y;
                    Ab[2] = (_Float16)xb.x; Ab[3] = (_Float16)xb.y;
                    Ab[4] = (_Float16)xc.x; Ab[5] = (_Float16)xc.y;
                    const int tn = (s + 1 < TT) ? s + 1 : s;   // prefetch x(t0+1)
                    const float2* p2 = (const float2*)(xp + (size_t)tn * DD);
                    xa = p2[0]; xb = p2[1]; xc = p2[2];
                }
            }

#define GATE(p) \
            f32x4 acc##p = {bias##p, bias##p, bias##p, bias##p}; \
            acc##p = MFMA_F16(Aa, Ba##p, acc##p); \
            acc##p = MFMA_F16(Ab, Bb##p, acc##p);
            GATE(0) GATE(1) GATE(2) GATE(3)

            // lane-local cell update; publish h (fp16) to the proper ring
#define UPD(r) { \
            float iv = sigm(acc0[r]); \
            float fv = sigm(acc1[r]); \
            float gv = tanh_f(acc2[r]); \
            float ov = sigm(acc3[r]); \
            cc##r = fv * cc##r + iv * gv; \
            float h_ = ov * tanh_f(cc##r); \
            if (L) { hL##r = h_; h1r[rsl][4 * q + r][u] = (_Float16)h_; } \
            else   {             h0r[wsl][4 * q + r][u] = (_Float16)h_; } }
            UPD(0) UPD(1) UPD(2) UPD(3)
        }
        __syncthreads();
    }

    // ---------------- LayerNorm epilogue ----------------
    if (L) {   // layer-1 waves hold fp32 h1(T-1)
        ln_s[4 * q + 0][u] = hL0;
        ln_s[4 * q + 1][u] = hL1;
        ln_s[4 * q + 2][u] = hL2;
        ln_s[4 * q + 3][u] = hL3;
    }
    __syncthreads();

    if (tid < 16) {
        const int m = tid;
        float s = 0.f, s2 = 0.f;
        #pragma unroll
        for (int k = 0; k < HD; ++k) {
            float v = ln_s[m][k];
            s += v; s2 += v * v;
        }
        float mu  = s * (1.0f / HD);
        float var = s2 * (1.0f / HD) - mu * mu;
        float rr  = rsqrtf(var + EPSL);
        float* op = out + (size_t)(b0 + m) * HD;
        #pragma unroll
        for (int k = 0; k < HD; ++k)
            op[k] = (ln_s[m][k] - mu) * rr * gamma[k] + beta[k];
    }
}

extern "C" void kernel_launch(void* const* d_in, const int* in_sizes, int n_in,
                              void* d_out, int out_size, void* d_ws, size_t ws_size,
                              hipStream_t stream) {
    const float* x     = (const float*)d_in[0];
    const float* W_ih0 = (const float*)d_in[1];
    const float* W_hh0 = (const float*)d_in[2];
    const float* b_ih0 = (const float*)d_in[3];
    const float* b_hh0 = (const float*)d_in[4];
    const float* W_ih1 = (const float*)d_in[5];
    const float* W_hh1 = (const float*)d_in[6];
    const float* b_ih1 = (const float*)d_in[7];
    const float* b_hh1 = (const float*)d_in[8];
    const float* gamma = (const float*)d_in[9];
    const float* beta  = (const float*)d_in[10];
    float* out = (float*)d_out;

    const int B = in_sizes[0] / (TT * DD);   // 4096
    lstm2_pipe<<<B / 16, 256, 0, stream>>>(x, W_ih0, W_hh0, b_ih0, b_hh0,
                                           W_ih1, W_hh1, b_ih1, b_hh1,
                                           gamma, beta, out);
}

// Round 4
// 415.522 us; speedup vs baseline: 5.1944x; 1.0977x over previous
//
#include <hip/hip_runtime.h>

#define TT   512
#define DD   6
#define HD   32
#define CH   32          // x-staging chunk (timesteps)
#define EPSL 1e-5f

typedef _Float16 half8 __attribute__((ext_vector_type(8)));
typedef __attribute__((ext_vector_type(4))) float f32x4;

#define MFMA_F16(a, b, c) __builtin_amdgcn_mfma_f32_16x16x32_f16((a), (b), (c), 0, 0, 0)

__device__ __forceinline__ float sigm(float v) {
    float e = __builtin_amdgcn_exp2f(-1.44269504f * v);
    return __builtin_amdgcn_rcpf(1.0f + e);
}
__device__ __forceinline__ float tanh_f(float v) {
    float e = __builtin_amdgcn_exp2f(-2.88539008f * v);
    return fmaf(2.0f, __builtin_amdgcn_rcpf(1.0f + e), -1.0f);
}

// ====================================================================
// Layer-pipelined 2-layer LSTM (R3 structure) + chunked LDS x-staging.
// R3 lesson: any outstanding global load is drained by the implicit
// s_waitcnt vmcnt(0) at EVERY __syncthreads -> per-iter x prefetch put a
// ~900cy cold-HBM wait on every step. Now x flows global->regs->LDS once
// per 32 steps; steady-state iterations have zero outstanding vm loads.
// ====================================================================
__global__ __launch_bounds__(256, 1) void lstm2_pipe(
    const float* __restrict__ x,      // (B,512,6)
    const float* __restrict__ W_ih0,  // (128,6)
    const float* __restrict__ W_hh0,  // (128,32)
    const float* __restrict__ b_ih0,
    const float* __restrict__ b_hh0,
    const float* __restrict__ W_ih1,  // (128,32)
    const float* __restrict__ W_hh1,  // (128,32)
    const float* __restrict__ b_ih1,
    const float* __restrict__ b_hh1,
    const float* __restrict__ gamma,
    const float* __restrict__ beta,
    float* __restrict__ out)          // (B,32)
{
    const int tid = threadIdx.x;
    const int w   = tid >> 6;
    const int L   = w >> 1;        // 0: layer-0 role, 1: layer-1 role
    const int uh  = w & 1;         // unit half
    const int ln  = tid & 63;
    const int q   = ln >> 4;
    const int n   = ln & 15;
    const int u   = 16 * uh + n;
    const int b0  = blockIdx.x << 4;

    // fp16 h rings: [buf][m=16][k=unit padded to 40]
    __shared__ __align__(16) _Float16 h0r[2][16][40];
    __shared__ __align__(16) _Float16 h1r[2][16][40];
    // x staging: [buf][t in chunk][m=16][8 halves (6 data + 2 zero)]  = 32 KB
    __shared__ __align__(16) _Float16 xs[2][CH][16][8];
    __shared__ float ln_s[16][33];

    {   // zero h rings and xs (zeros in xs pads d=6,7 persist; stores only touch d<6)
        unsigned* p0 = (unsigned*)&h0r[0][0][0];
        for (int i = tid; i < (int)(sizeof(h0r) / 4); i += 256) p0[i] = 0u;
        unsigned* p1 = (unsigned*)&h1r[0][0][0];
        for (int i = tid; i < (int)(sizeof(h1r) / 4); i += 256) p1[i] = 0u;
        unsigned* p2 = (unsigned*)&xs[0][0][0][0];
        for (int i = tid; i < (int)(sizeof(xs) / 4); i += 256) p2[i] = 0u;
    }

    // ---------------- weight B-frags (fp16, 1-term) ----------------
    const float* Wa = L ? W_ih1 : W_hh0;
    const float* bi = L ? b_ih1 : b_ih0;
    const float* bh = L ? b_hh1 : b_hh0;

#define SETUP(p) \
    half8 Ba##p, Bb##p; float bias##p; { \
        const int g = 32 * (p) + u; \
        const float4* r4 = (const float4*)(Wa + g * 32 + 8 * q); \
        float4 va = r4[0], vb = r4[1]; \
        Ba##p = half8{(_Float16)va.x, (_Float16)va.y, (_Float16)va.z, (_Float16)va.w, \
                      (_Float16)vb.x, (_Float16)vb.y, (_Float16)vb.z, (_Float16)vb.w}; \
        Bb##p = half8{0, 0, 0, 0, 0, 0, 0, 0}; \
        if (L) { \
            const float4* s4 = (const float4*)(W_hh1 + g * 32 + 8 * q); \
            float4 sa = s4[0], sb = s4[1]; \
            Bb##p = half8{(_Float16)sa.x, (_Float16)sa.y, (_Float16)sa.z, (_Float16)sa.w, \
                          (_Float16)sb.x, (_Float16)sb.y, (_Float16)sb.z, (_Float16)sb.w}; \
        } else if (q == 0) { \
            const float* xw = W_ih0 + g * 6; \
            Bb##p[0] = (_Float16)xw[0]; Bb##p[1] = (_Float16)xw[1]; \
            Bb##p[2] = (_Float16)xw[2]; Bb##p[3] = (_Float16)xw[3]; \
            Bb##p[4] = (_Float16)xw[4]; Bb##p[5] = (_Float16)xw[5]; \
        } \
        bias##p = bi[g] + bh[g]; \
    }
    SETUP(0) SETUP(1) SETUP(2) SETUP(3)

    // ---------------- x chunk machinery ----------------
    // chunk = CH steps x 16 batch x 6 floats = 768 float4; 3 float4/thread.
    // thread i (i = tid + 256k): m = i/48, j = i%48 -> floats [4j..4j+4) of
    // batch row m's 192-float chunk segment. Fully coalesced 16B loads.
    const int m0 = (tid       ) / 48, j0 = (tid       ) % 48;
    const int m1 = (tid + 256 ) / 48, j1 = (tid + 256 ) % 48;
    const int m2 = (tid + 512 ) / 48, j2 = (tid + 512 ) % 48;
    float4 xr0, xr1, xr2;

#define XLOAD(ch) { \
        const float* cb = x + (size_t)b0 * (TT * DD) + (ch) * (CH * DD); \
        xr0 = *(const float4*)(cb + (size_t)m0 * (TT * DD) + 4 * j0); \
        xr1 = *(const float4*)(cb + (size_t)m1 * (TT * DD) + 4 * j1); \
        xr2 = *(const float4*)(cb + (size_t)m2 * (TT * DD) + 4 * j2); }

#define XSTORE(buf) { \
        _Float16* xb_ = &xs[(buf)][0][0][0]; \
        { int f = 4 * j0; float4 v = xr0; \
          xb_[((f+0)/6)*128 + m0*8 + ((f+0)%6)] = (_Float16)v.x; \
          xb_[((f+1)/6)*128 + m0*8 + ((f+1)%6)] = (_Float16)v.y; \
          xb_[((f+2)/6)*128 + m0*8 + ((f+2)%6)] = (_Float16)v.z; \
          xb_[((f+3)/6)*128 + m0*8 + ((f+3)%6)] = (_Float16)v.w; } \
        { int f = 4 * j1; float4 v = xr1; \
          xb_[((f+0)/6)*128 + m1*8 + ((f+0)%6)] = (_Float16)v.x; \
          xb_[((f+1)/6)*128 + m1*8 + ((f+1)%6)] = (_Float16)v.y; \
          xb_[((f+2)/6)*128 + m1*8 + ((f+2)%6)] = (_Float16)v.z; \
          xb_[((f+3)/6)*128 + m1*8 + ((f+3)%6)] = (_Float16)v.w; } \
        { int f = 4 * j2; float4 v = xr2; \
          xb_[((f+0)/6)*128 + m2*8 + ((f+0)%6)] = (_Float16)v.x; \
          xb_[((f+1)/6)*128 + m2*8 + ((f+1)%6)] = (_Float16)v.y; \
          xb_[((f+2)/6)*128 + m2*8 + ((f+2)%6)] = (_Float16)v.z; \
          xb_[((f+3)/6)*128 + m2*8 + ((f+3)%6)] = (_Float16)v.w; } }

    // prologue: chunk 0 -> buf 0
    XLOAD(0)
    XSTORE(0)

    float cc0 = 0.f, cc1 = 0.f, cc2 = 0.f, cc3 = 0.f;   // cell state (lane-local)
    float hL0 = 0.f, hL1 = 0.f, hL2 = 0.f, hL3 = 0.f;   // fp32 h1 (LN epilogue)

    __syncthreads();

    #pragma unroll 1
    for (int s = 0; s <= TT; ++s) {
        const int wsl = s & 1;
        const int rsl = wsl ^ 1;

        // issue next chunk's global loads right after the barrier; they are
        // drained at THIS iteration's end barrier (1-in-32 iterations).
        if ((s & (CH - 1)) == 0 && s < TT - CH) {
            XLOAD((s >> 5) + 1)
        }

        const bool active = L ? (s >= 1) : (s < TT);
        if (active) {
            half8 Aa = *(const half8*)&h0r[rsl][n][8 * q];
            half8 Ab;
            if (L) {
                Ab = *(const half8*)&h1r[wsl][n][8 * q];
            } else {
                Ab = half8{0, 0, 0, 0, 0, 0, 0, 0};
                if (q == 0)
                    Ab = *(const half8*)&xs[(s >> 5) & 1][s & (CH - 1)][n][0];
            }

#define GATE(p) \
            f32x4 acc##p = {bias##p, bias##p, bias##p, bias##p}; \
            acc##p = MFMA_F16(Aa, Ba##p, acc##p); \
            acc##p = MFMA_F16(Ab, Bb##p, acc##p);
            GATE(0) GATE(1) GATE(2) GATE(3)

#define UPD(r) { \
            float iv = sigm(acc0[r]); \
            float fv = sigm(acc1[r]); \
            float gv = tanh_f(acc2[r]); \
            float ov = sigm(acc3[r]); \
            cc##r = fv * cc##r + iv * gv; \
            float h_ = ov * tanh_f(cc##r); \
            if (L) { hL##r = h_; h1r[rsl][4 * q + r][u] = (_Float16)h_; } \
            else   {             h0r[wsl][4 * q + r][u] = (_Float16)h_; } }
            UPD(0) UPD(1) UPD(2) UPD(3)
        }

        // convert+store the in-flight chunk to the other xs buffer at chunk end
        if ((s & (CH - 1)) == CH - 1 && s < TT - 1) {
            XSTORE(((s >> 5) + 1) & 1)
        }

        __syncthreads();
    }

    // ---------------- LayerNorm epilogue ----------------
    if (L) {
        ln_s[4 * q + 0][u] = hL0;
        ln_s[4 * q + 1][u] = hL1;
        ln_s[4 * q + 2][u] = hL2;
        ln_s[4 * q + 3][u] = hL3;
    }
    __syncthreads();

    if (tid < 16) {
        const int m = tid;
        float s = 0.f, s2 = 0.f;
        #pragma unroll
        for (int k = 0; k < HD; ++k) {
            float v = ln_s[m][k];
            s += v; s2 += v * v;
        }
        float mu  = s * (1.0f / HD);
        float var = s2 * (1.0f / HD) - mu * mu;
        float rr  = rsqrtf(var + EPSL);
        float* op = out + (size_t)(b0 + m) * HD;
        #pragma unroll
        for (int k = 0; k < HD; ++k)
            op[k] = (ln_s[m][k] - mu) * rr * gamma[k] + beta[k];
    }
}

extern "C" void kernel_launch(void* const* d_in, const int* in_sizes, int n_in,
                              void* d_out, int out_size, void* d_ws, size_t ws_size,
                              hipStream_t stream) {
    const float* x     = (const float*)d_in[0];
    const float* W_ih0 = (const float*)d_in[1];
    const float* W_hh0 = (const float*)d_in[2];
    const float* b_ih0 = (const float*)d_in[3];
    const float* b_hh0 = (const float*)d_in[4];
    const float* W_ih1 = (const float*)d_in[5];
    const float* W_hh1 = (const float*)d_in[6];
    const float* b_ih1 = (const float*)d_in[7];
    const float* b_hh1 = (const float*)d_in[8];
    const float* gamma = (const float*)d_in[9];
    const float* beta  = (const float*)d_in[10];
    float* out = (float*)d_out;

    const int B = in_sizes[0] / (TT * DD);   // 4096
    lstm2_pipe<<<B / 16, 256, 0, stream>>>(x, W_ih0, W_hh0, b_ih0, b_hh0,
                                           W_ih1, W_hh1, b_ih1, b_hh1,
                                           gamma, beta, out);
}